// Round 7
// baseline (211.934 us; speedup 1.0000x reference)
//
#include <hip/hip_runtime.h>

#define C_ 512
#define L_ 784
#define K_ 64
#define EPS_ 1e-12f

typedef _Float16 half_t;
typedef _Float16 half8 __attribute__((ext_vector_type(8)));
typedef _Float16 half4 __attribute__((ext_vector_type(4)));
typedef float float4v __attribute__((ext_vector_type(4)));

// ---------------------------------------------------------------------------
// Kernel A (MFMA fp16): logits[k][l] = sum_c w[k][c]*x[n][c][l], 64-wide
// l-tile, softmax over k, store a (fp16) + partial asum.
// grid (13, 64) block 256 (4 waves; wave wv owns k-tile 16*wv).
// w A-frags preloaded to REGISTERS once (16 half8 = 64 VGPR) — R6's kA
// restaged w 8x/block (411 MB L2 traffic) and was latency-bound at 66us.
// MFMA 16x16x32_f16: A-frag m=lane&15->k, kk=(lane>>4)*8+j->c;
// B-frag n=lane&15->l, same kk; D row=(lane>>4)*4+r->k, col=lane&15->l.
// ---------------------------------------------------------------------------
__global__ __launch_bounds__(256) void kA(const float* __restrict__ x,
                                          const float* __restrict__ w,
                                          half_t* __restrict__ a_out,     // [64][64][784] fp16
                                          float* __restrict__ asum_part) {// [64][13][64]
    __shared__ union {
        half_t xh[64 * 72];   // [l][c-chunk 64] stride 72 (144 B rows, 16B-aligned)
        float  sl[64 * 65];   // [k][l] logits/softmax (used after chunk loop)
    } sm;
    const int t    = threadIdx.x;
    const int n    = blockIdx.y;
    const int lt   = blockIdx.x;
    const int l0   = lt * 64;
    const int lw   = (L_ - l0 < 64) ? (L_ - l0) : 64;   // 64, except 16 for lt=12
    const int wv   = t >> 6;
    const int lane = t & 63;
    const int m16  = lane & 15;
    const int q    = lane >> 4;

    // ---- preload w fragments (one-time; w is L2/L3-hot across blocks) ----
    half8 wf[16];
    {
        const float* wr = w + (size_t)(16 * wv + m16) * C_ + 8 * q;
#pragma unroll
        for (int cc = 0; cc < 16; cc++) {
            float4v f0 = *(const float4v*)(wr + 32 * cc);
            float4v f1 = *(const float4v*)(wr + 32 * cc + 4);
            wf[cc] = half8{(half_t)f0.x, (half_t)f0.y, (half_t)f0.z, (half_t)f0.w,
                           (half_t)f1.x, (half_t)f1.y, (half_t)f1.z, (half_t)f1.w};
        }
    }

    float4v acc[4] = {{0.f,0.f,0.f,0.f},{0.f,0.f,0.f,0.f},{0.f,0.f,0.f,0.f},{0.f,0.f,0.f,0.f}};

    const float* xb = x + (size_t)n * (C_ * L_) + l0;
    // staging map: e = t + 256*i -> c = e>>4 (0..63), lq = e&15 (l-quad)
    const int sc = t >> 4, slq = t & 15;

    // prefetch chunk 0
    float4v fx[4];
#pragma unroll
    for (int i = 0; i < 4; i++) {
        int c = sc, lq = slq;  // i adds 16 c per step: c = sc + 16*i
        c = sc + 16 * i;
        float4v f = {0.f, 0.f, 0.f, 0.f};
        if (4 * lq < lw) f = *(const float4v*)(xb + (size_t)c * L_ + 4 * lq);
        fx[i] = f;
    }

    for (int cc = 0; cc < 8; ++cc) {
        // write staged regs -> LDS (fp16, transposed [l][c])
#pragma unroll
        for (int i = 0; i < 4; i++) {
            int c = sc + 16 * i;
            int l = 4 * slq;
            sm.xh[(l + 0) * 72 + c] = (half_t)fx[i].x;
            sm.xh[(l + 1) * 72 + c] = (half_t)fx[i].y;
            sm.xh[(l + 2) * 72 + c] = (half_t)fx[i].z;
            sm.xh[(l + 3) * 72 + c] = (half_t)fx[i].w;
        }
        __syncthreads();
        // issue next chunk's global loads (overlap with MFMA below)
        if (cc < 7) {
            const float* xc = xb + (size_t)(cc + 1) * 64 * L_;
#pragma unroll
            for (int i = 0; i < 4; i++) {
                int c = sc + 16 * i;
                float4v f = {0.f, 0.f, 0.f, 0.f};
                if (4 * slq < lw) f = *(const float4v*)(xc + (size_t)c * L_ + 4 * slq);
                fx[i] = f;
            }
        }
#pragma unroll
        for (int s = 0; s < 2; s++) {
            half8 A = wf[2 * cc + s];
#pragma unroll
            for (int jt = 0; jt < 4; jt++) {
                half8 B = *(const half8*)&sm.xh[(16 * jt + m16) * 72 + 32 * s + 8 * q];
                acc[jt] = __builtin_amdgcn_mfma_f32_16x16x32_f16(A, B, acc[jt], 0, 0, 0);
            }
        }
        __syncthreads();
    }

    // dump logits to sl[k][l]
#pragma unroll
    for (int jt = 0; jt < 4; jt++)
#pragma unroll
        for (int r = 0; r < 4; r++)
            sm.sl[(16 * wv + 4 * q + r) * 65 + 16 * jt + m16] = acc[jt][r];
    __syncthreads();

    // softmax over k, one l-column per thread
    if (t < 64 && t < lw) {
        const int l = t;
        float mx = -1e30f;
        for (int k = 0; k < 64; k++) mx = fmaxf(mx, sm.sl[k * 65 + l]);
        float s = 0.f;
        for (int k = 0; k < 64; k++) {
            float e = __expf(sm.sl[k * 65 + l] - mx);
            sm.sl[k * 65 + l] = e;
            s += e;
        }
        float inv = 1.f / s;
        for (int k = 0; k < 64; k++) sm.sl[k * 65 + l] *= inv;
    }
    __syncthreads();

    // partial asum per k over valid l of this tile
    if (t < 64) {
        float s = 0.f;
        for (int l = 0; l < lw; l++) s += sm.sl[t * 65 + l];
        asum_part[((size_t)n * 13 + lt) * 64 + t] = s;
    }

    // store a fp16: 64k x 64l = 1024 half4 units, 4/thread
    half_t* ao = a_out + (size_t)n * (K_ * L_);
#pragma unroll
    for (int i = 0; i < 4; i++) {
        int u = t + 256 * i;
        int k = u >> 4, lq = u & 15;
        int l = 4 * lq;
        if (l < lw) {
            half4 h = { (half_t)sm.sl[k * 65 + l],     (half_t)sm.sl[k * 65 + l + 1],
                        (half_t)sm.sl[k * 65 + l + 2], (half_t)sm.sl[k * 65 + l + 3] };
            *(half4*)(ao + (size_t)k * L_ + l0 + l) = h;
        }
    }
}

// ---------------------------------------------------------------------------
// Kernel B (MFMA fp16): agg[k][c] = sum_l a[k][l]*x[c][l], c-tile 64.
// grid (8, 64) block 512 (8 waves: kw = wv&3 k-tile, ch = wv>>2 c-half).
// l-chunks of 64 (13 iters, zero-padded tail: 784 = 12*64+16).
// Register prefetch of next chunk overlaps MFMA. No transposes: x is [c][l],
// a is [k][l], both consumed l-contiguous.
// ---------------------------------------------------------------------------
__global__ __launch_bounds__(512) void kB(const float* __restrict__ x,
                                          const half_t* __restrict__ a_in,  // [64][64][784]
                                          float* __restrict__ agg) {        // [64][64][512]
    __shared__ half_t ah[64 * 72];   // [k][l-chunk 64]
    __shared__ half_t xh[64 * 72];   // [c][l-chunk 64]
    const int t    = threadIdx.x;
    const int n    = blockIdx.y;
    const int c0   = blockIdx.x * 64;
    const int wv   = t >> 6;
    const int lane = t & 63;
    const int m16  = lane & 15;
    const int q    = lane >> 4;
    const int kw   = wv & 3;
    const int ch   = wv >> 2;

    float4v acc[2] = {{0.f,0.f,0.f,0.f},{0.f,0.f,0.f,0.f}};

    const float*  xb = x    + (size_t)n * (C_ * L_);
    const half_t* ab = a_in + (size_t)n * (K_ * L_);

    // staging maps:
    //   a: 512 half8 units, 1/thread: k = t>>3, ho = t&7 (l = 8*ho)
    //   x: 1024 float4 units, 2/thread: e = t+512i: c = e>>4, lq = e&15
    const int ak = t >> 3, aho = t & 7;
    const int xc0i = t >> 4, xlq = t & 15;

    half8  pa;
    float4v px[2];
    {
        int l = 8 * aho;
        pa = (half8)(half_t)0.f;
        if (l < L_) pa = *(const half8*)(ab + (size_t)ak * L_ + l);
#pragma unroll
        for (int i = 0; i < 2; i++) {
            int c = xc0i + 32 * i;
            float4v f = {0.f,0.f,0.f,0.f};
            if (4 * xlq < L_) f = *(const float4v*)(xb + (size_t)(c0 + c) * L_ + 4 * xlq);
            px[i] = f;
        }
    }

    for (int lt = 0; lt < 13; ++lt) {
        // write staged -> LDS
        *(half8*)&ah[ak * 72 + 8 * aho] = pa;
#pragma unroll
        for (int i = 0; i < 2; i++) {
            int c = xc0i + 32 * i;
            half4 h = { (half_t)px[i].x, (half_t)px[i].y, (half_t)px[i].z, (half_t)px[i].w };
            *(half4*)&xh[c * 72 + 4 * xlq] = h;
        }
        __syncthreads();
        // prefetch next chunk
        if (lt < 12) {
            const int l0n = (lt + 1) * 64;
            int la = l0n + 8 * aho;
            pa = (half8)(half_t)0.f;
            if (la < L_) pa = *(const half8*)(ab + (size_t)ak * L_ + la);
#pragma unroll
            for (int i = 0; i < 2; i++) {
                int c = xc0i + 32 * i;
                int lx = l0n + 4 * xlq;
                float4v f = {0.f,0.f,0.f,0.f};
                if (lx < L_) f = *(const float4v*)(xb + (size_t)(c0 + c) * L_ + lx);
                px[i] = f;
            }
        }
#pragma unroll
        for (int s = 0; s < 2; s++) {
            half8 A = *(const half8*)&ah[(16 * kw + m16) * 72 + 32 * s + 8 * q];
#pragma unroll
            for (int ct = 0; ct < 2; ct++) {
                half8 B = *(const half8*)&xh[(32 * ch + 16 * ct + m16) * 72 + 32 * s + 8 * q];
                acc[ct] = __builtin_amdgcn_mfma_f32_16x16x32_f16(A, B, acc[ct], 0, 0, 0);
            }
        }
        __syncthreads();
    }

    float* ap = agg + (size_t)n * (K_ * C_) + c0;
#pragma unroll
    for (int ct = 0; ct < 2; ct++)
#pragma unroll
        for (int r = 0; r < 4; r++)
            ap[(size_t)(16 * kw + 4 * q + r) * C_ + 32 * ch + 16 * ct + m16] = acc[ct][r];
}

// ---------------------------------------------------------------------------
// Kernel C: vlad = agg - asum*cent ; intra-normalize per (n,k) over C;
// global norm is exactly 8 (64 unit rows): out = vlad/(||row||*8). fp32 out.
// grid (8, 64), block 256 (4 waves, 2 rows each).
// ---------------------------------------------------------------------------
__global__ __launch_bounds__(256) void kC(const float* __restrict__ agg,
                                          const float* __restrict__ cent,
                                          const float* __restrict__ asum_part,
                                          float* __restrict__ out) {
    __shared__ float asumS[8];
    const int t  = threadIdx.x;
    const int n  = blockIdx.y;
    const int k0 = blockIdx.x * 8;
    if (t < 8) {
        float s = 0.f;
        for (int j = 0; j < 13; j++) s += asum_part[((size_t)n * 13 + j) * 64 + k0 + t];
        asumS[t] = s;
    }
    __syncthreads();
    const int wv = t >> 6;
    const int lane = t & 63;
    for (int r = wv; r < 8; r += 4) {
        const int k = k0 + r;
        const float as = asumS[r];
        const float* ap = agg + (size_t)n * (K_ * C_) + (size_t)k * C_;
        const float* cp = cent + (size_t)k * C_;
        float v[8];
        float ss = 0.f;
#pragma unroll
        for (int j = 0; j < 8; j++) {
            int c = lane + 64 * j;
            float val = ap[c] - as * cp[c];
            v[j] = val;
            ss += val * val;
        }
#pragma unroll
        for (int off = 32; off; off >>= 1) ss += __shfl_xor(ss, off, 64);
        float scale = 1.f / (fmaxf(sqrtf(ss), EPS_) * 8.f);
        float* op = out + (size_t)n * (K_ * C_) + (size_t)k * C_;
#pragma unroll
        for (int j = 0; j < 8; j++) op[lane + 64 * j] = v[j] * scale;
    }
}

extern "C" void kernel_launch(void* const* d_in, const int* in_sizes, int n_in,
                              void* d_out, int out_size, void* d_ws, size_t ws_size,
                              hipStream_t stream) {
    (void)in_sizes; (void)n_in; (void)out_size; (void)ws_size;
    const float* x    = (const float*)d_in[0];   // (64, 512, 28, 28) fp32
    const float* w    = (const float*)d_in[1];   // (64, 512) fp32
    const float* cent = (const float*)d_in[2];   // (64, 512) fp32
    float* out = (float*)d_out;                  // (64, 32768) fp32

    // ws: a fp16 6.42 MB ; agg f32 8.39 MB ; asum f32 [64*13*64] 213 KB
    char* base = (char*)d_ws;
    half_t* a    = (half_t*)base;
    float*  agg  = (float*)(base + ((size_t)K_ * L_ * 64 * 2 + 255) / 256 * 256);
    float*  asum = agg + (size_t)64 * K_ * C_;

    kA<<<dim3(13, 64), 256, 0, stream>>>(x, w, a, asum);
    kB<<<dim3(8, 64),  512, 0, stream>>>(x, a, agg);
    kC<<<dim3(8, 64),  256, 0, stream>>>(agg, cent, asum, out);
}